// Round 1
// baseline (138.813 us; speedup 1.0000x reference)
//
#include <hip/hip_runtime.h>
#include <math.h>

// Problem constants (from reference):
//   B=2, H=W=64, C=64, N=4096, NUM_LEVELS=4, RADIUS=3 -> K=49
//   out: (B, N, 4*49*64) f32 = 102,760,448 floats
// Pyramid (normalized fmap2, cascaded 2x antialiased bilinear downsample)
// stored in d_ws as f32:
//   L0: 2*64*64*64 = 524288 floats @ 0
//   L1: 2*32*32*64 = 131072 floats @ 524288
//   L2: 2*16*16*64 =  32768 floats @ 655360
//   L3: 2* 8* 8*64 =   8192 floats @ 688128   (total 696320 floats = 2.79 MB)

#define NTOT_SAMPLE_THREADS 25690112  // out_size/4

__global__ __launch_bounds__(256) void normalize_kernel(
    const float* __restrict__ in, float* __restrict__ out) {
  int gtid = blockIdx.x * 256 + threadIdx.x;
  int wave = gtid >> 6;          // pixel index, 0 .. 8191
  int lane = gtid & 63;          // channel
  float v = in[wave * 64 + lane];
  float ss = v * v;
  #pragma unroll
  for (int m = 32; m >= 1; m >>= 1) ss += __shfl_xor(ss, m);
  out[wave * 64 + lane] = v / (sqrtf(ss) + 1e-6f);
}

// 2x antialiased bilinear downsample (jax.image.resize semantics):
// output i <- input taps {2i-1, 2i, 2i+1, 2i+2}, base weights
// {0.25,0.75,0.75,0.25}; out-of-range taps dropped, weights renormalized.
__global__ __launch_bounds__(256) void downsample_kernel(
    const float* __restrict__ in, float* __restrict__ out, int Si) {
  int So = Si >> 1;
  int gtid = blockIdx.x * 256 + threadIdx.x;
  int wave = gtid >> 6;
  int lane = gtid & 63;
  int ox = wave % So;
  int t  = wave / So;
  int oy = t % So;
  int b  = t / So;

  int xs[4], ys[4];
  float wx[4], wy[4];
  const float base0 = 0.25f, base1 = 0.75f;
  float bw[4] = {base0, base1, base1, base0};
  float sx = 0.f, sy = 0.f;
  #pragma unroll
  for (int tt = 0; tt < 4; tt++) {
    int jx = 2 * ox - 1 + tt;
    bool vx = (jx >= 0) && (jx < Si);
    xs[tt] = vx ? jx : 0;
    wx[tt] = vx ? bw[tt] : 0.f;
    sx += wx[tt];
    int jy = 2 * oy - 1 + tt;
    bool vy = (jy >= 0) && (jy < Si);
    ys[tt] = vy ? jy : 0;
    wy[tt] = vy ? bw[tt] : 0.f;
    sy += wy[tt];
  }
  float ix = 1.f / sx, iy = 1.f / sy;
  #pragma unroll
  for (int tt = 0; tt < 4; tt++) { wx[tt] *= ix; wy[tt] *= iy; }

  float acc = 0.f;
  #pragma unroll
  for (int a = 0; a < 4; a++) {
    const float* rp = in + ((long)(b * Si + ys[a]) * Si) * 64 + lane;
    float row = 0.f;
    #pragma unroll
    for (int tt = 0; tt < 4; tt++) row += wx[tt] * rp[xs[tt] * 64];
    acc += wy[a] * row;
  }
  out[((long)(b * So + oy) * So + ox) * 64 + lane] = acc;
}

__global__ __launch_bounds__(256) void sample_kernel(
    const float* __restrict__ pyr, const float* __restrict__ coords,
    float* __restrict__ out) {
  unsigned tid = blockIdx.x * 256u + threadIdx.x;
  // tid = ((((b*4096+n)*4 + l)*49) + k)*16 + c4   -> out float4 index = tid
  unsigned c4 = tid & 15u;
  unsigned t  = tid >> 4;
  unsigned k  = t % 49u;
  t /= 49u;
  unsigned l = t & 3u;
  t >>= 2;
  unsigned n = t & 4095u;
  unsigned b = t >> 12;

  unsigned bn = (b << 12) | n;
  float cx = coords[bn * 2 + 0];
  float cy = coords[bn * 2 + 1];

  int Wl = 64 >> l;
  float sc = 1.0f / (float)(1 << l);   // exact power of two
  float fmx = (float)(Wl - 1);
  int dx = (int)(k % 7u) - 3;
  int dy = (int)(k / 7u) - 3;

  float x = fminf(fmaxf(cx * sc + (float)dx, 0.f), fmx);
  float y = fminf(fmaxf(cy * sc + (float)dy, 0.f), fmx);

  int x0 = (int)floorf(x);
  int y0 = (int)floorf(y);
  int x1 = min(x0 + 1, Wl - 1);
  int y1 = min(y0 + 1, Wl - 1);
  float fx0 = (float)x0, fy0 = (float)y0;
  float fx1 = (float)x1, fy1 = (float)y1;
  // NOTE: weights use the CLIPPED x1/y1 (reference quirk: all-zero at edge)
  float wa = (fx1 - x) * (fy1 - y);
  float wb = (fx1 - x) * (y - fy0);
  float wc = (x - fx0) * (fy1 - y);
  float wd = (x - fx0) * (y - fy0);

  const int lvl_base[4] = {0, 524288, 655360, 688128};
  long lb = lvl_base[l];
  long row0 = lb + (((long)(b * Wl + y0) * Wl) << 6);
  long row1 = lb + (((long)(b * Wl + y1) * Wl) << 6);
  const float4* pa = (const float4*)(pyr + row0 + ((long)x0 << 6)) + c4;
  const float4* pb = (const float4*)(pyr + row1 + ((long)x0 << 6)) + c4;
  const float4* pc = (const float4*)(pyr + row0 + ((long)x1 << 6)) + c4;
  const float4* pd = (const float4*)(pyr + row1 + ((long)x1 << 6)) + c4;

  float4 Ia = *pa, Ib = *pb, Ic = *pc, Id = *pd;
  float4 o;
  o.x = wa * Ia.x + wb * Ib.x + wc * Ic.x + wd * Id.x;
  o.y = wa * Ia.y + wb * Ib.y + wc * Ic.y + wd * Id.y;
  o.z = wa * Ia.z + wb * Ib.z + wc * Ic.z + wd * Id.z;
  o.w = wa * Ia.w + wb * Ib.w + wc * Ic.w + wd * Id.w;

  ((float4*)out)[tid] = o;
}

extern "C" void kernel_launch(void* const* d_in, const int* in_sizes, int n_in,
                              void* d_out, int out_size, void* d_ws, size_t ws_size,
                              hipStream_t stream) {
  // d_in[0] = fmap1 (UNUSED by the reference: normalized then discarded)
  const float* fmap2  = (const float*)d_in[1];
  const float* coords = (const float*)d_in[2];
  float* out = (float*)d_out;
  float* pyr = (float*)d_ws;

  // L0: normalize fmap2 over channels. 8192 pixels, 1 wave each.
  normalize_kernel<<<2048, 256, 0, stream>>>(fmap2, pyr);
  // Cascaded downsamples. blocks = B*So*So*64/256
  downsample_kernel<<<512, 256, 0, stream>>>(pyr,            pyr + 524288, 64);
  downsample_kernel<<<128, 256, 0, stream>>>(pyr + 524288,   pyr + 655360, 32);
  downsample_kernel<<< 32, 256, 0, stream>>>(pyr + 655360,   pyr + 688128, 16);
  // Main sampling: one thread per output float4.
  sample_kernel<<<NTOT_SAMPLE_THREADS / 256, 256, 0, stream>>>(pyr, coords, out);
}

// Round 2
// 87.357 us; speedup vs baseline: 1.5890x; 1.5890x over previous
//
#include <hip/hip_runtime.h>
#include <math.h>

// Problem constants: B=2, H=W=64, C=64, N=4096, NUM_LEVELS=4, RADIUS=3 -> K=49
// out: (B, N, 4*49*64) f32 = 102,760,448 floats (411 MB)
// Pyramid in d_ws (f32):
//   L0: 2*64*64*64 @ 0        (524288 floats)
//   L1: 2*32*32*64 @ 524288   (131072)
//   L2: 2*16*16*64 @ 655360   ( 32768)
//   L3: 2* 8* 8*64 @ 688128   (  8192)
// float4 bases: 0, 131072, 163840, 172032  == (524288 - (524288>>2l))/3

__global__ __launch_bounds__(256) void normalize_kernel(
    const float* __restrict__ in, float* __restrict__ out) {
  int gtid = blockIdx.x * 256 + threadIdx.x;
  int wave = gtid >> 6;          // pixel index, 0 .. 8191
  int lane = gtid & 63;          // channel
  float v = in[wave * 64 + lane];
  float ss = v * v;
  #pragma unroll
  for (int m = 32; m >= 1; m >>= 1) ss += __shfl_xor(ss, m);
  out[wave * 64 + lane] = v / (sqrtf(ss) + 1e-6f);
}

// 2x antialiased bilinear downsample (jax.image.resize semantics)
__global__ __launch_bounds__(256) void downsample_kernel(
    const float* __restrict__ in, float* __restrict__ out, int Si) {
  int So = Si >> 1;
  int gtid = blockIdx.x * 256 + threadIdx.x;
  int wave = gtid >> 6;
  int lane = gtid & 63;
  int ox = wave % So;
  int t  = wave / So;
  int oy = t % So;
  int b  = t / So;

  int xs[4], ys[4];
  float wx[4], wy[4];
  float bw[4] = {0.25f, 0.75f, 0.75f, 0.25f};
  float sx = 0.f, sy = 0.f;
  #pragma unroll
  for (int tt = 0; tt < 4; tt++) {
    int jx = 2 * ox - 1 + tt;
    bool vx = (jx >= 0) && (jx < Si);
    xs[tt] = vx ? jx : 0;
    wx[tt] = vx ? bw[tt] : 0.f;
    sx += wx[tt];
    int jy = 2 * oy - 1 + tt;
    bool vy = (jy >= 0) && (jy < Si);
    ys[tt] = vy ? jy : 0;
    wy[tt] = vy ? bw[tt] : 0.f;
    sy += wy[tt];
  }
  float ix = 1.f / sx, iy = 1.f / sy;
  #pragma unroll
  for (int tt = 0; tt < 4; tt++) { wx[tt] *= ix; wy[tt] *= iy; }

  float acc = 0.f;
  #pragma unroll
  for (int a = 0; a < 4; a++) {
    const float* rp = in + ((long)(b * Si + ys[a]) * Si) * 64 + lane;
    float row = 0.f;
    #pragma unroll
    for (int tt = 0; tt < 4; tt++) row += wx[tt] * rp[xs[tt] * 64];
    acc += wy[a] * row;
  }
  out[((long)(b * So + oy) * So + ox) * 64 + lane] = acc;
}

// One block per (b, n, level). Stage 9x9x64 window in LDS, precompute
// the 49 offset weights/indices once, then emit 49*16 float4 outputs.
__global__ __launch_bounds__(256) void corr_sample_lds(
    const float* __restrict__ pyr, const float* __restrict__ coords,
    float* __restrict__ out) {
  __shared__ float4 win[1296];   // [row*9+col][c4]  9*9*16 float4 = 20.7 KB
  __shared__ float4 kw[49];      // per-offset weights (wa,wb,wc,wd)
  __shared__ int4   ko[49];      // per-offset float4-indices into win

  unsigned bid = blockIdx.x;
  unsigned l  = bid & 3u;
  unsigned bn = bid >> 2;        // 0..8191
  unsigned b  = bn >> 12;
  int tid = threadIdx.x;

  int Wl = 64 >> l;
  float sc  = 1.0f / (float)(1 << l);     // exact power of two
  float fmx = (float)(Wl - 1);
  // pyramid base in float4 units: (524288 - (524288 >> 2l)) / 3
  unsigned base4 = (524288u - (524288u >> (2u * l))) / 3u;

  // Block-uniform coordinate -> scalar loads
  float cx = coords[bn * 2 + 0];
  float cy = coords[bn * 2 + 1];
  float cxs = cx * sc, cys = cy * sc;
  int fx = (int)floorf(cxs), fy = (int)floorf(cys);
  int xlo = max(fx - 3, 0), ylo = max(fy - 3, 0);

  // Phase A: stage window (clamped at borders). 1296 float4s, coalesced.
  const float4* src = (const float4*)pyr;
  for (int i = tid; i < 1296; i += 256) {
    int c4  = i & 15;
    int t   = i >> 4;          // 0..80 = row*9+col
    int col = t % 9;
    int row = t / 9;
    int cg = min(xlo + col, Wl - 1);
    int rg = min(ylo + row, Wl - 1);
    unsigned g4 = base4 + (((unsigned)(b * Wl + rg) * (unsigned)Wl + (unsigned)cg) << 4) + c4;
    win[i] = src[g4];
  }

  // Phase A2: per-offset weights/indices (reference quirk preserved:
  // weights use CLIPPED x1/y1 -> all-zero sample at exact border)
  if (tid < 49) {
    int dxi = tid % 7 - 3, dyi = tid / 7 - 3;
    float x = fminf(fmaxf(cxs + (float)dxi, 0.f), fmx);
    float y = fminf(fmaxf(cys + (float)dyi, 0.f), fmx);
    int x0 = (int)floorf(x), y0 = (int)floorf(y);
    int x1 = min(x0 + 1, Wl - 1), y1 = min(y0 + 1, Wl - 1);
    float fx0 = (float)x0, fy0 = (float)y0;
    float fx1 = (float)x1, fy1 = (float)y1;
    kw[tid] = make_float4((fx1 - x) * (fy1 - y), (fx1 - x) * (y - fy0),
                          (x - fx0) * (fy1 - y), (x - fx0) * (y - fy0));
    int ix0 = x0 - xlo, ix1 = x1 - xlo;
    int iy0 = y0 - ylo, iy1 = y1 - ylo;
    ko[tid] = make_int4((iy0 * 9 + ix0) << 4, (iy1 * 9 + ix0) << 4,
                        (iy0 * 9 + ix1) << 4, (iy1 * 9 + ix1) << 4);
  }
  __syncthreads();

  // Phase B: 49*16 = 784 output float4s from LDS.
  unsigned ob4 = bn * 3136u + l * 784u;   // float4 index of block's output
  for (int i = tid; i < 784; i += 256) {
    int c4 = i & 15;
    int k  = i >> 4;
    float4 w = kw[k];          // broadcast
    int4   o = ko[k];          // broadcast
    float4 Ia = win[o.x + c4], Ib = win[o.y + c4];
    float4 Ic = win[o.z + c4], Id = win[o.w + c4];
    float4 r;
    r.x = w.x * Ia.x + w.y * Ib.x + w.z * Ic.x + w.w * Id.x;
    r.y = w.x * Ia.y + w.y * Ib.y + w.z * Ic.y + w.w * Id.y;
    r.z = w.x * Ia.z + w.y * Ib.z + w.z * Ic.z + w.w * Id.z;
    r.w = w.x * Ia.w + w.y * Ib.w + w.z * Ic.w + w.w * Id.w;
    ((float4*)out)[ob4 + i] = r;
  }
}

extern "C" void kernel_launch(void* const* d_in, const int* in_sizes, int n_in,
                              void* d_out, int out_size, void* d_ws, size_t ws_size,
                              hipStream_t stream) {
  // d_in[0] = fmap1 (normalized then discarded by the reference)
  const float* fmap2  = (const float*)d_in[1];
  const float* coords = (const float*)d_in[2];
  float* out = (float*)d_out;
  float* pyr = (float*)d_ws;

  normalize_kernel<<<2048, 256, 0, stream>>>(fmap2, pyr);
  downsample_kernel<<<512, 256, 0, stream>>>(pyr,          pyr + 524288, 64);
  downsample_kernel<<<128, 256, 0, stream>>>(pyr + 524288, pyr + 655360, 32);
  downsample_kernel<<< 32, 256, 0, stream>>>(pyr + 655360, pyr + 688128, 16);
  // One block per (b,n,level): 2*4096*4 = 32768 blocks.
  corr_sample_lds<<<32768, 256, 0, stream>>>(pyr, coords, out);
}

// Round 3
// 86.911 us; speedup vs baseline: 1.5972x; 1.0051x over previous
//
#include <hip/hip_runtime.h>
#include <math.h>

// Problem constants: B=2, H=W=64, C=64, N=4096, NUM_LEVELS=4, RADIUS=3 -> K=49
// out: (B, N, 4*49*64) f32 = 102,760,448 floats (411 MB)
// Pyramid in d_ws (f32):
//   L0: 2*64*64*64 @ 0        (524288 floats)
//   L1: 2*32*32*64 @ 524288   (131072)
//   L2: 2*16*16*64 @ 655360   ( 32768)
//   L3: 2* 8* 8*64 @ 688128   (  8192)
// float4 base per level l: (524288 - (524288>>2l))/3 = {0,131072,163840,172032}

__global__ __launch_bounds__(256) void normalize_kernel(
    const float* __restrict__ in, float* __restrict__ out) {
  int gtid = blockIdx.x * 256 + threadIdx.x;
  int wave = gtid >> 6;          // pixel index, 0 .. 8191
  int lane = gtid & 63;          // channel
  float v = in[wave * 64 + lane];
  float ss = v * v;
  #pragma unroll
  for (int m = 32; m >= 1; m >>= 1) ss += __shfl_xor(ss, m);
  out[wave * 64 + lane] = v / (sqrtf(ss) + 1e-6f);
}

// 2x antialiased bilinear downsample (jax.image.resize semantics)
__global__ __launch_bounds__(256) void downsample_kernel(
    const float* __restrict__ in, float* __restrict__ out, int Si) {
  int So = Si >> 1;
  int gtid = blockIdx.x * 256 + threadIdx.x;
  int wave = gtid >> 6;
  int lane = gtid & 63;
  int ox = wave % So;
  int t  = wave / So;
  int oy = t % So;
  int b  = t / So;

  int xs[4], ys[4];
  float wx[4], wy[4];
  float bw[4] = {0.25f, 0.75f, 0.75f, 0.25f};
  float sx = 0.f, sy = 0.f;
  #pragma unroll
  for (int tt = 0; tt < 4; tt++) {
    int jx = 2 * ox - 1 + tt;
    bool vx = (jx >= 0) && (jx < Si);
    xs[tt] = vx ? jx : 0;
    wx[tt] = vx ? bw[tt] : 0.f;
    sx += wx[tt];
    int jy = 2 * oy - 1 + tt;
    bool vy = (jy >= 0) && (jy < Si);
    ys[tt] = vy ? jy : 0;
    wy[tt] = vy ? bw[tt] : 0.f;
    sy += wy[tt];
  }
  float ix = 1.f / sx, iy = 1.f / sy;
  #pragma unroll
  for (int tt = 0; tt < 4; tt++) { wx[tt] *= ix; wy[tt] *= iy; }

  float acc = 0.f;
  #pragma unroll
  for (int a = 0; a < 4; a++) {
    const float* rp = in + ((long)(b * Si + ys[a]) * Si) * 64 + lane;
    float row = 0.f;
    #pragma unroll
    for (int tt = 0; tt < 4; tt++) row += wx[tt] * rp[xs[tt] * 64];
    acc += wy[a] * row;
  }
  out[((long)(b * So + oy) * So + ox) * 64 + lane] = acc;
}

// Register dx-walk sampler: one block per bn=(b,n), 448 threads.
// thread = (dyi*4 + l)*16 + c4 ; each thread emits 7 float4 outputs (dx walk).
// y0/y1/wy fixed per thread; previous x1-column texel pair is reused as the
// new x0 pair (x0==px check is exact under clipping / fp rounding edges).
__global__ __launch_bounds__(448, 4) void corr_sample_reg(
    const float* __restrict__ pyr, const float* __restrict__ coords,
    float* __restrict__ out) {
  unsigned bn = blockIdx.x;      // 0..8191
  unsigned b  = bn >> 12;
  int t   = threadIdx.x;
  int c4  = t & 15;
  int g   = t >> 4;              // 0..27
  int l   = g & 3;
  int dyi = g >> 2;              // 0..6

  int Wl = 64 >> l;
  float sc  = 1.0f / (float)(1 << l);    // exact power of two
  float fmx = (float)(Wl - 1);
  unsigned base4 = (524288u - (524288u >> (2 * l))) / 3u;

  float cx = coords[bn * 2 + 0];
  float cy = coords[bn * 2 + 1];
  float cxs = cx * sc, cys = cy * sc;

  // Reference quirk preserved: weights use CLIPPED x1/y1 -> exact zero at edge.
  float y = fminf(fmaxf(cys + (float)(dyi - 3), 0.f), fmx);
  int y0 = (int)floorf(y);
  int y1 = min(y0 + 1, Wl - 1);
  float wy0 = (float)y1 - y;
  float wy1 = y - (float)y0;

  const float4* p4 = (const float4*)pyr;
  unsigned pixb = (unsigned)(b * Wl * Wl);
  unsigned r0 = base4 + ((pixb + (unsigned)(y0 * Wl)) << 4) + (unsigned)c4;
  unsigned r1 = base4 + ((pixb + (unsigned)(y1 * Wl)) << 4) + (unsigned)c4;

  unsigned ob = bn * 3136u + (unsigned)l * 784u + ((unsigned)(dyi * 7) << 4) + (unsigned)c4;
  float4* o4 = (float4*)out;

  int px = -1;                   // x1 >= 1 always, so -1 never falsely matches
  float4 a0 = make_float4(0.f, 0.f, 0.f, 0.f), a1 = a0;
  #pragma unroll
  for (int dxi = 0; dxi < 7; ++dxi) {
    float x = fminf(fmaxf(cxs + (float)(dxi - 3), 0.f), fmx);
    int x0 = (int)floorf(x);
    int x1 = min(x0 + 1, Wl - 1);
    float wx0 = (float)x1 - x;
    float wx1 = x - (float)x0;

    float4 b0, b1;
    if (x0 == px) { b0 = a0; b1 = a1; }
    else { b0 = p4[r0 + ((unsigned)x0 << 4)]; b1 = p4[r1 + ((unsigned)x0 << 4)]; }
    a0 = p4[r0 + ((unsigned)x1 << 4)];
    a1 = p4[r1 + ((unsigned)x1 << 4)];
    px = x1;

    float4 r;
    r.x = wx0 * (wy0 * b0.x + wy1 * b1.x) + wx1 * (wy0 * a0.x + wy1 * a1.x);
    r.y = wx0 * (wy0 * b0.y + wy1 * b1.y) + wx1 * (wy0 * a0.y + wy1 * a1.y);
    r.z = wx0 * (wy0 * b0.z + wy1 * b1.z) + wx1 * (wy0 * a0.z + wy1 * a1.z);
    r.w = wx0 * (wy0 * b0.w + wy1 * b1.w) + wx1 * (wy0 * a0.w + wy1 * a1.w);
    o4[ob + (unsigned)(dxi << 4)] = r;
  }
}

extern "C" void kernel_launch(void* const* d_in, const int* in_sizes, int n_in,
                              void* d_out, int out_size, void* d_ws, size_t ws_size,
                              hipStream_t stream) {
  // d_in[0] = fmap1 (normalized then discarded by the reference)
  const float* fmap2  = (const float*)d_in[1];
  const float* coords = (const float*)d_in[2];
  float* out = (float*)d_out;
  float* pyr = (float*)d_ws;

  normalize_kernel<<<2048, 256, 0, stream>>>(fmap2, pyr);
  downsample_kernel<<<512, 256, 0, stream>>>(pyr,          pyr + 524288, 64);
  downsample_kernel<<<128, 256, 0, stream>>>(pyr + 524288, pyr + 655360, 32);
  downsample_kernel<<< 32, 256, 0, stream>>>(pyr + 655360, pyr + 688128, 16);
  // One block per (b,n): 8192 blocks x 448 threads; no LDS, no barriers.
  corr_sample_reg<<<8192, 448, 0, stream>>>(pyr, coords, out);
}